// Round 15
// baseline (3283.398 us; speedup 1.0000x reference)
//
#include <hip/hip_runtime.h>
#include <hip/hip_cooperative_groups.h>
#include <hip/hip_bf16.h>
#include <math.h>

namespace cg = cooperative_groups;

#define Hd 5
#define NN 20000
#define EE 320000
#define NBATCH 4
#define BNH (NBATCH * NN * Hd) /* 400000 */

typedef __attribute__((ext_vector_type(8))) short short8;
typedef __attribute__((ext_vector_type(4))) float f32x4;
typedef __attribute__((ext_vector_type(4))) unsigned int uint4v;

__device__ __forceinline__ float sigmoidf_(float v) {
    return 1.0f / (1.0f + expf(-v));
}

__device__ __forceinline__ unsigned short bf16bits(float v) {
    __hip_bfloat16 h = __float2bfloat16(v);
    return *(unsigned short*)&h;
}
__device__ __forceinline__ float bf16tof(unsigned short u) {
    __hip_bfloat16 h = *(__hip_bfloat16*)&u;
    return __bfloat162float(h);
}

// ===========================================================================
// one-time per-launch edge sort by index_out (counting sort) — verified r4/r5
// ===========================================================================
__global__ void k_hist(const int* __restrict__ iout, unsigned* __restrict__ cnt) {
    int t = blockIdx.x * 256 + threadIdx.x;
    atomicAdd(&cnt[iout[t]], 1u);
}

__global__ void k_scan(const unsigned* __restrict__ cnt, unsigned* __restrict__ row) {
    __shared__ unsigned part[256];
    int i = threadIdx.x;
    unsigned s = 0;
    if (i < 250) {
        for (int k = 0; k < 80; ++k) s += cnt[i * 80 + k];
    }
    part[i] = s;
    __syncthreads();
    for (int off = 1; off < 256; off <<= 1) {
        unsigned v = part[i];
        unsigned u = (i >= off) ? part[i - off] : 0u;
        __syncthreads();
        part[i] = v + u;
        __syncthreads();
    }
    unsigned run = (i == 0) ? 0u : part[i - 1];
    if (i < 250) {
        for (int k = 0; k < 80; ++k) {
            row[i * 80 + k] = run;
            run += cnt[i * 80 + k];
        }
    }
}

__global__ void k_scatter(const int* __restrict__ iout,
                          const unsigned* __restrict__ row,
                          unsigned* __restrict__ cur,
                          unsigned* __restrict__ perm) {
    int t = blockIdx.x * 256 + threadIdx.x;
    int io = iout[t];
    unsigned pos = row[io] + atomicAdd(&cur[io], 1u);
    perm[pos] = (unsigned)t;
}

__global__ void k_mat(const unsigned* __restrict__ perm,
                      const int* __restrict__ iout, const int* __restrict__ iin,
                      const float* __restrict__ Jm,
                      int* __restrict__ sout, int* __restrict__ sin,
                      float* __restrict__ sJ) {
    int t = blockIdx.x * 256 + threadIdx.x;
    unsigned e = perm[t];
    sout[t] = iout[e];
    sin[t]  = iin[e];
#pragma unroll
    for (int b = 0; b < NBATCH; ++b)
        sJ[(size_t)b * EE + t] = Jm[(size_t)b * EE + e];
}

// ===========================================================================
// prep: A-fragment images for ALL THREE MLP layers (r12-verified maps).
// ===========================================================================
__global__ void k_wfrag(const float* __restrict__ W1, const float* __restrict__ W2,
                        const float* __restrict__ W3,
                        unsigned short* __restrict__ af1,
                        unsigned short* __restrict__ af2,
                        unsigned short* __restrict__ af3) {
    int t = blockIdx.x * 256 + threadIdx.x;
    if (t < 2048) {
        int j  = t & 7;
        int l  = (t >> 3) & 63;
        int qt = t >> 9;
        int g  = l >> 4;
        int q  = qt * 16 + (l & 15);
        float base = (j < 7) ? W1[j * 64 + q] : (W1[7 * 64 + q] - W1[8 * 64 + q]);
        unsigned short w0 = bf16bits(base);
        af1[t] = (g < 2) ? w0 : bf16bits(base - bf16tof(w0));
    }
    if (t < 4096) {
        int j  = t & 7;
        int l  = (t >> 3) & 63;
        int kt = (t >> 9) & 1;
        int qt = t >> 10;
        int g  = l >> 4;
        int p  = l & 15;
        int nk = (j >> 1) * 16 + 4 * g + 2 * kt + (j & 1);
        int no = (qt & 1) * 32 + 8 * (p >> 2) + 4 * (qt >> 1) + (p & 3);
        af2[t] = bf16bits(W2[nk * 64 + no]);
    }
    if (t < 1024) {
        int j  = t & 7;
        int l  = (t >> 3) & 63;
        int kt = t >> 9;
        int i  = l & 15;
        int g3 = l >> 4;
        int n  = kt * 32 + 8 * g3 + j;
        af3[t] = (i < 5) ? bf16bits(W3[n * 5 + i]) : (unsigned short)0;
    }
}

// ===========================================================================
// per-wave message unit — r12-verified body verbatim (64 sorted edges x 1
// batch, all 3 layers on matrix pipe, segmented scan + tail atomics).
// ===========================================================================
__device__ __forceinline__ void msg_unit(
    int lane, int e0, int bb,
    const float* __restrict__ sJ, const float* __restrict__ bnode,
    const int* __restrict__ sin, const int* __restrict__ sout,
    const float* __restrict__ b1,
    const unsigned short* __restrict__ af1,
    const unsigned short* __restrict__ af2,
    const unsigned short* __restrict__ af3,
    const float* __restrict__ b2, const float* __restrict__ b3,
    const float* __restrict__ h1, float* __restrict__ sCur)
{
    int g = lane >> 4;
    int c = lane & 15;
    int e = e0 + lane;

    int io = sout[e];
    int ii = sin[e];
    size_t hoff = ((size_t)bb * NN + io) * Hd;

    float xf[8];
#pragma unroll
    for (int i = 0; i < Hd; ++i) xf[i] = h1[hoff + i];
    xf[5] = bnode[bb * NN + ii];
    xf[6] = bnode[bb * NN + io];
    xf[7] = sJ[(size_t)bb * EE + e];

    // ---- layer-1 B fragments: x_hi (trunc) / x_lo (residual, RNE) ----
    uint4v B1l[4];
#pragma unroll
    for (int et = 0; et < 4; ++et) {
        float xe[8];
#pragma unroll
        for (int f = 0; f < 8; ++f) xe[f] = __shfl(xf[f], et * 16 + c, 64);

        uint4v hiP, loP;
#pragma unroll
        for (int j2 = 0; j2 < 4; ++j2) {
            float va = xe[2 * j2], vb = xe[2 * j2 + 1];
            unsigned ta = __float_as_uint(va), tb = __float_as_uint(vb);
            unsigned ha = ta & 0xFFFF0000u, hb = tb & 0xFFFF0000u;
            hiP[j2] = hb | (ta >> 16);
            float ra = va - __uint_as_float(ha);
            float rb = vb - __uint_as_float(hb);
            unsigned pk;
            asm("v_cvt_pk_bf16_f32 %0, %1, %2" : "=v"(pk) : "v"(ra), "v"(rb));
            loP[j2] = pk;
        }
#pragma unroll
        for (int d = 0; d < 4; ++d) B1l[et][d] = (g & 1) ? loP[d] : hiP[d];
    }

    // ---- layer-1 MFMA ----
    const short8* pA1 = (const short8*)af1;
    f32x4 D1[4][4];
#pragma unroll
    for (int qt = 0; qt < 4; ++qt) {
        float4 bb1 = *(const float4*)(b1 + qt * 16 + 4 * g);
        short8 a1f = pA1[qt * 64 + lane];
#pragma unroll
        for (int et = 0; et < 4; ++et) {
            f32x4 dinit = (f32x4){bb1.x, bb1.y, bb1.z, bb1.w};
            D1[qt][et] = __builtin_amdgcn_mfma_f32_16x16x32_bf16(
                a1f, __builtin_bit_cast(short8, B1l[et]), dinit, 0, 0, 0);
        }
    }

    // ---- handoff 1->2 ----
    short8 B2[4][2];
#pragma unroll
    for (int et = 0; et < 4; ++et) {
        uint4v w0, w1;
#pragma unroll
        for (int qt = 0; qt < 4; ++qt) {
            float r0 = fmaxf(D1[qt][et][0], 0.0f);
            float r1 = fmaxf(D1[qt][et][1], 0.0f);
            float r2 = fmaxf(D1[qt][et][2], 0.0f);
            float r3 = fmaxf(D1[qt][et][3], 0.0f);
            unsigned p0, p1;
            asm("v_cvt_pk_bf16_f32 %0, %1, %2" : "=v"(p0) : "v"(r0), "v"(r1));
            asm("v_cvt_pk_bf16_f32 %0, %1, %2" : "=v"(p1) : "v"(r2), "v"(r3));
            w0[qt] = p0;
            w1[qt] = p1;
        }
        B2[et][0] = __builtin_bit_cast(short8, w0);
        B2[et][1] = __builtin_bit_cast(short8, w1);
    }

    // ---- layers 2+3 ----
    const short8* pA2 = (const short8*)af2;
    const short8* pA3 = (const short8*)af3;

    f32x4 D3[4];
#pragma unroll
    for (int et = 0; et < 4; ++et) D3[et] = (f32x4){0.f, 0.f, 0.f, 0.f};

#pragma unroll
    for (int half = 0; half < 2; ++half) {
        float4 ba  = *(const float4*)(b2 + half * 32 + 8 * g);
        float4 bbv = *(const float4*)(b2 + half * 32 + 8 * g + 4);
        f32x4 D2a[4], D2b[4];
#pragma unroll
        for (int et = 0; et < 4; ++et) {
            D2a[et] = (f32x4){ba.x, ba.y, ba.z, ba.w};
            D2b[et] = (f32x4){bbv.x, bbv.y, bbv.z, bbv.w};
        }
#pragma unroll
        for (int kt2 = 0; kt2 < 2; ++kt2) {
            short8 a0a = pA2[(half * 2 + kt2) * 64 + lane];
            short8 a0b = pA2[((half + 2) * 2 + kt2) * 64 + lane];
#pragma unroll
            for (int et = 0; et < 4; ++et) {
                D2a[et] = __builtin_amdgcn_mfma_f32_16x16x32_bf16(a0a, B2[et][kt2], D2a[et], 0, 0, 0);
                D2b[et] = __builtin_amdgcn_mfma_f32_16x16x32_bf16(a0b, B2[et][kt2], D2b[et], 0, 0, 0);
            }
        }
        short8 a3 = pA3[half * 64 + lane];
#pragma unroll
        for (int et = 0; et < 4; ++et) {
            float x0 = fmaxf(D2a[et][0], 0.0f), x1 = fmaxf(D2a[et][1], 0.0f);
            float x2 = fmaxf(D2a[et][2], 0.0f), x3 = fmaxf(D2a[et][3], 0.0f);
            float y0 = fmaxf(D2b[et][0], 0.0f), y1 = fmaxf(D2b[et][1], 0.0f);
            float y2 = fmaxf(D2b[et][2], 0.0f), y3 = fmaxf(D2b[et][3], 0.0f);
            uint4v pk;
            unsigned p0, p1, p2, p3;
            asm("v_cvt_pk_bf16_f32 %0, %1, %2" : "=v"(p0) : "v"(x0), "v"(x1));
            asm("v_cvt_pk_bf16_f32 %0, %1, %2" : "=v"(p1) : "v"(x2), "v"(x3));
            asm("v_cvt_pk_bf16_f32 %0, %1, %2" : "=v"(p2) : "v"(y0), "v"(y1));
            asm("v_cvt_pk_bf16_f32 %0, %1, %2" : "=v"(p3) : "v"(y2), "v"(y3));
            pk[0] = p0; pk[1] = p1; pk[2] = p2; pk[3] = p3;
            D3[et] = __builtin_amdgcn_mfma_f32_16x16x32_bf16(
                a3, __builtin_bit_cast(short8, pk), D3[et], 0, 0, 0);
        }
    }

    // ---- redistribution ----
    float m[Hd];
#pragma unroll
    for (int i = 0; i < 4; ++i) {
        float p0 = __shfl(D3[0][i], c, 64);
        float p1 = __shfl(D3[1][i], c, 64);
        float p2 = __shfl(D3[2][i], c, 64);
        float p3 = __shfl(D3[3][i], c, 64);
        m[i] = ((g == 0) ? p0 : (g == 1) ? p1 : (g == 2) ? p2 : p3) + b3[i];
    }
    {
        float p0 = __shfl(D3[0][0], 16 + c, 64);
        float p1 = __shfl(D3[1][0], 16 + c, 64);
        float p2 = __shfl(D3[2][0], 16 + c, 64);
        float p3 = __shfl(D3[3][0], 16 + c, 64);
        m[4] = ((g == 0) ? p0 : (g == 1) ? p1 : (g == 2) ? p2 : p3) + b3[4];
    }

    // ---- wave segmented sum over sorted keys ----
#pragma unroll
    for (int off = 1; off < 64; off <<= 1) {
        int ko = __shfl_up(io, off, 64);
        bool add = (lane >= off) && (ko == io);
#pragma unroll
        for (int i = 0; i < Hd; ++i) {
            float u = __shfl_up(m[i], off, 64);
            if (add) m[i] += u;
        }
    }
    int nk = __shfl_down(io, 1, 64);
    bool tail = (lane == 63) || (nk != io);
    if (tail) {
#pragma unroll
        for (int i = 0; i < Hd; ++i) atomicAdd(&sCur[hoff + i], m[i]);
    }
}

// ===========================================================================
// per-node GRU update — r12-verified body as a device function.
// ===========================================================================
__device__ __forceinline__ void node_update(
    int t, int zeroPrev,
    const float* __restrict__ gzW, const float* __restrict__ gzb,
    const float* __restrict__ grW, const float* __restrict__ grb,
    const float* __restrict__ ghW, const float* __restrict__ ghb,
    float* __restrict__ h1, float* __restrict__ m0,
    float* __restrict__ s0buf, const float* __restrict__ s1buf)
{
    size_t off = (size_t)t * Hd;

    float h1v[Hd], m0v[Hd], m1v[Hd];
#pragma unroll
    for (int i = 0; i < Hd; ++i) {
        h1v[i] = h1[off + i];
        float m0n = m0[off + i] + s0buf[off + i];
        m0v[i] = m0n;
        m1v[i] = m0n + s1buf[off + i];
        m0[off + i] = m0n;
        if (zeroPrev) s0buf[off + i] = 0.0f;
    }

    float a[15];
#pragma unroll
    for (int i = 0; i < Hd; ++i) { a[i] = h1v[i]; a[5 + i] = m0v[i]; a[10 + i] = m1v[i]; }

    float z[Hd], r[Hd];
#pragma unroll
    for (int i = 0; i < Hd; ++i) {
        float tz = gzb[i], tr = grb[i];
#pragma unroll
        for (int j = 0; j < 15; ++j) {
            tz = fmaf(a[j], gzW[j * Hd + i], tz);
            tr = fmaf(a[j], grW[j * Hd + i], tr);
        }
        z[i] = sigmoidf_(tz);
        r[i] = sigmoidf_(tr);
    }

    float joined[15];
#pragma unroll
    for (int i = 0; i < Hd; ++i) { joined[i] = r[i] * h1v[i]; joined[5 + i] = m0v[i]; joined[10 + i] = m1v[i]; }

#pragma unroll
    for (int i = 0; i < Hd; ++i) {
        float th = ghb[i];
#pragma unroll
        for (int j = 0; j < 15; ++j) th = fmaf(joined[j], ghW[j * Hd + i], th);
        float hh = tanhf(th);
        h1[off + i] = (1.0f - z[i]) * h1v[i] + z[i] * hh;
    }
}

// ===========================================================================
// persistent cooperative kernel: all 10 (msg + node) steps with grid.sync().
// Removes 19 dispatch drain/ramp boundaries; grid sized to exact co-residency
// (grid = 256 * maxBlocksPerCU) so msg-phase wave residency is guaranteed.
// ===========================================================================
__global__ void __launch_bounds__(256, 4) fused_kernel(
    const float* sJ, const float* bnode, const int* sin, const int* sout,
    const float* b1, const unsigned short* af1, const unsigned short* af2,
    const unsigned short* af3, const float* b2, const float* b3,
    const float* gzW, const float* gzb, const float* grW, const float* grb,
    const float* ghW, const float* ghb,
    float* h1, float* m0, float* sA, float* sB)
{
    cg::grid_group grid = cg::this_grid();
    int lane  = threadIdx.x & 63;
    int wid   = threadIdx.x >> 6;
    int gwave = blockIdx.x * 4 + wid;
    int nwave = gridDim.x * 4;
    int gtid  = blockIdx.x * 256 + threadIdx.x;
    int nthr  = gridDim.x * 256;

    for (int s = 0; s < 10; ++s) {
        float* sCur  = (s & 1) ? sB : sA;
        float* sPrev = (s == 0) ? sCur : ((s & 1) ? sA : sB);

        // msg phase: 20000 wave-units (5000 edge-groups x 4 batches)
        for (int u = gwave; u < 5000 * NBATCH; u += nwave) {
            int bb = u / 5000;
            int eg = u - bb * 5000;
            msg_unit(lane, eg * 64, bb, sJ, bnode, sin, sout,
                     b1, af1, af2, af3, b2, b3, h1, sCur);
        }
        __threadfence();
        grid.sync();

        // node phase: 80000 node-units
        for (int t = gtid; t < NBATCH * NN; t += nthr) {
            node_update(t, (s == 0) ? 0 : 1, gzW, gzb, grW, grb, ghW, ghb,
                        h1, m0, sPrev, sCur);
        }
        __threadfence();
        grid.sync();
    }
}

// ===========================================================================
// fallback multi-kernel path (r14-verified) — used if cooperative launch fails
// ===========================================================================
__global__ void __launch_bounds__(256, 4) msg_kernel(
    const float* __restrict__ sJ, const float* __restrict__ bnode,
    const int* __restrict__ sin, const int* __restrict__ sout,
    const float* __restrict__ b1,
    const unsigned short* __restrict__ af1,
    const unsigned short* __restrict__ af2,
    const unsigned short* __restrict__ af3,
    const float* __restrict__ b2, const float* __restrict__ b3,
    const float* __restrict__ h1,
    float* __restrict__ sCur)
{
    int wid  = threadIdx.x >> 6;
    int lane = threadIdx.x & 63;
    msg_unit(lane, blockIdx.x * 256 + wid * 64, blockIdx.y,
             sJ, bnode, sin, sout, b1, af1, af2, af3, b2, b3, h1, sCur);
}

__global__ void node_kernel(
    const float* __restrict__ gzW, const float* __restrict__ gzb,
    const float* __restrict__ grW, const float* __restrict__ grb,
    const float* __restrict__ ghW, const float* __restrict__ ghb,
    float* __restrict__ h1, float* __restrict__ m0,
    float* __restrict__ s0buf, const float* __restrict__ s1buf,
    int zeroPrev)
{
    int t = blockIdx.x * 256 + threadIdx.x;
    if (t >= NBATCH * NN) return;
    node_update(t, zeroPrev, gzW, gzb, grW, grb, ghW, ghb, h1, m0, s0buf, s1buf);
}

// ---------------------------------------------------------------------------
// output MLP (unchanged, verified; runs once)
// ---------------------------------------------------------------------------
__global__ void __launch_bounds__(256, 1) out_kernel(
    const float* __restrict__ bnode, const float* __restrict__ h1,
    const float* __restrict__ oW1, const float* __restrict__ ob1,
    const float* __restrict__ oW2, const float* __restrict__ ob2,
    const float* __restrict__ oW3, const float* __restrict__ ob3,
    float* __restrict__ out)
{
    int t = blockIdx.x * 256 + threadIdx.x;
    if (t >= NBATCH * NN) return;

    float x[6];
#pragma unroll
    for (int i = 0; i < Hd; ++i) x[i] = h1[(size_t)t * Hd + i];
    x[5] = bnode[t];

    float acc[64];
#pragma unroll
    for (int q = 0; q < 64; ++q) acc[q] = ob2[q];

#pragma unroll 2
    for (int j = 0; j < 64; ++j) {
        float v = ob1[j];
#pragma unroll
        for (int f = 0; f < 6; ++f) v = fmaf(x[f], oW1[f * 64 + j], v);
        v = fmaxf(v, 0.0f);
        const float* __restrict__ w2r = oW2 + j * 64;
#pragma unroll
        for (int q = 0; q < 64; ++q) acc[q] = fmaf(v, w2r[q], acc[q]);
    }

    float o = ob3[0];
#pragma unroll
    for (int q = 0; q < 64; ++q) o = fmaf(fmaxf(acc[q], 0.0f), oW3[q], o);
    out[t] = sigmoidf_(o);
}

// ---------------------------------------------------------------------------
extern "C" void kernel_launch(void* const* d_in, const int* in_sizes, int n_in,
                              void* d_out, int out_size, void* d_ws, size_t ws_size,
                              hipStream_t stream) {
    const float* Jm    = (const float*)d_in[0];
    const float* bnode = (const float*)d_in[1];
    const int*   iin   = (const int*)d_in[2];
    const int*   iout  = (const int*)d_in[3];
    const float* mW1 = (const float*)d_in[4];
    const float* mb1 = (const float*)d_in[5];
    const float* mW2 = (const float*)d_in[6];
    const float* mb2 = (const float*)d_in[7];
    const float* mW3 = (const float*)d_in[8];
    const float* mb3 = (const float*)d_in[9];
    const float* gzW = (const float*)d_in[10];
    const float* gzb = (const float*)d_in[11];
    const float* grW = (const float*)d_in[12];
    const float* grb = (const float*)d_in[13];
    const float* ghW = (const float*)d_in[14];
    const float* ghb = (const float*)d_in[15];
    const float* oW1 = (const float*)d_in[16];
    const float* ob1 = (const float*)d_in[17];
    const float* oW2 = (const float*)d_in[18];
    const float* ob2 = (const float*)d_in[19];
    const float* oW3 = (const float*)d_in[20];
    const float* ob3 = (const float*)d_in[21];

    float* ws = (float*)d_ws;
    float* h1 = ws;
    float* m0 = ws + (size_t)BNH;
    float* sA = ws + (size_t)2 * BNH;
    float* sB = ws + (size_t)3 * BNH;
    unsigned* cnt  = (unsigned*)(ws + (size_t)4 * BNH);
    unsigned* cur  = cnt + NN;
    unsigned* row  = cur + NN;
    unsigned* perm = row + NN;
    int*      sout = (int*)(perm + EE);
    int*      sin  = sout + EE;
    float*    sJ   = (float*)(sin + EE);           // NBATCH*EE floats
    unsigned short* af1 = (unsigned short*)(sJ + (size_t)NBATCH * EE);  // 2048
    unsigned short* af2 = af1 + 2048;                                   // 4096
    unsigned short* af3 = af2 + 4096;                                   // 1024

    // zero h1, m0, sA, sB, cnt, cur (contiguous)
    hipMemsetAsync(d_ws, 0, ((size_t)4 * BNH + 2 * NN) * sizeof(float), stream);

    // one-time (per launch): sort edges by index_out + build weight frag images
    k_hist<<<EE / 256, 256, 0, stream>>>(iout, cnt);
    k_scan<<<1, 256, 0, stream>>>(cnt, row);
    k_scatter<<<EE / 256, 256, 0, stream>>>(iout, row, cur, perm);
    k_mat<<<EE / 256, 256, 0, stream>>>(perm, iout, iin, Jm, sout, sin, sJ);
    k_wfrag<<<20, 256, 0, stream>>>(mW1, mW2, mW3, af1, af2, af3);

    // ---- persistent cooperative path ----
    bool coop_ok = false;
    int maxB = 0;
    if (hipOccupancyMaxActiveBlocksPerMultiprocessor(&maxB, fused_kernel, 256, 0)
            == hipSuccess && maxB > 0) {
        int grid = 256 * maxB;          // exact co-residency (256 CUs)
        if (grid > 5000) grid = 5000;
        const float* a_sJ = sJ; const float* a_bn = bnode;
        const int* a_sin = sin; const int* a_sout = sout;
        const float* a_b1 = mb1;
        const unsigned short* a_af1 = af1;
        const unsigned short* a_af2 = af2;
        const unsigned short* a_af3 = af3;
        const float* a_b2 = mb2; const float* a_b3 = mb3;
        const float* a_gzW = gzW; const float* a_gzb = gzb;
        const float* a_grW = grW; const float* a_grb = grb;
        const float* a_ghW = ghW; const float* a_ghb = ghb;
        float* a_h1 = h1; float* a_m0 = m0; float* a_sA = sA; float* a_sB = sB;
        void* args[] = { &a_sJ, &a_bn, &a_sin, &a_sout, &a_b1, &a_af1, &a_af2,
                         &a_af3, &a_b2, &a_b3, &a_gzW, &a_gzb, &a_grW, &a_grb,
                         &a_ghW, &a_ghb, &a_h1, &a_m0, &a_sA, &a_sB };
        if (hipLaunchCooperativeKernel(fused_kernel, dim3(grid), dim3(256),
                                       args, 0, stream) == hipSuccess)
            coop_ok = true;
    }

    // ---- fallback: r14-verified multi-kernel loop ----
    if (!coop_ok) {
        dim3 mgrid(EE / 256, NBATCH);
        int ngrid = (NBATCH * NN + 255) / 256;
        float* buf[2] = { sA, sB };
        for (int s = 0; s < 10; ++s) {
            float* sCur  = buf[s & 1];
            float* sPrev = (s == 0) ? sCur : buf[(s + 1) & 1];
            msg_kernel<<<mgrid, 256, 0, stream>>>(sJ, bnode, sin, sout,
                                                  mb1, af1, af2, af3,
                                                  mb2, mb3, h1, sCur);
            node_kernel<<<ngrid, 256, 0, stream>>>(gzW, gzb, grW, grb, ghW, ghb,
                                                   h1, m0, sPrev, sCur,
                                                   (s == 0) ? 0 : 1);
        }
    }

    int ngrid2 = (NBATCH * NN + 255) / 256;
    out_kernel<<<ngrid2, 256, 0, stream>>>(bnode, h1,
                                           oW1, ob1, oW2, ob2, oW3, ob3,
                                           (float*)d_out);
}

// Round 16
// 570.748 us; speedup vs baseline: 5.7528x; 5.7528x over previous
//
#include <hip/hip_runtime.h>
#include <hip/hip_bf16.h>
#include <math.h>

#define Hd 5
#define NN 20000
#define EE 320000
#define NBATCH 4
#define BNH (NBATCH * NN * Hd) /* 400000 */

typedef __attribute__((ext_vector_type(8))) short short8;
typedef __attribute__((ext_vector_type(4))) float f32x4;
typedef __attribute__((ext_vector_type(4))) unsigned int uint4v;

__device__ __forceinline__ float sigmoidf_(float v) {
    return 1.0f / (1.0f + expf(-v));
}

__device__ __forceinline__ unsigned short bf16bits(float v) {
    __hip_bfloat16 h = __float2bfloat16(v);
    return *(unsigned short*)&h;
}
__device__ __forceinline__ float bf16tof(unsigned short u) {
    __hip_bfloat16 h = *(__hip_bfloat16*)&u;
    return __bfloat162float(h);
}

// ===========================================================================
// one-time per-launch edge sort by index_out (counting sort) — verified r4/r5
// ===========================================================================
__global__ void k_hist(const int* __restrict__ iout, unsigned* __restrict__ cnt) {
    int t = blockIdx.x * 256 + threadIdx.x;
    atomicAdd(&cnt[iout[t]], 1u);
}

__global__ void k_scan(const unsigned* __restrict__ cnt, unsigned* __restrict__ row) {
    __shared__ unsigned part[256];
    int i = threadIdx.x;
    unsigned s = 0;
    if (i < 250) {
        for (int k = 0; k < 80; ++k) s += cnt[i * 80 + k];
    }
    part[i] = s;
    __syncthreads();
    for (int off = 1; off < 256; off <<= 1) {
        unsigned v = part[i];
        unsigned u = (i >= off) ? part[i - off] : 0u;
        __syncthreads();
        part[i] = v + u;
        __syncthreads();
    }
    unsigned run = (i == 0) ? 0u : part[i - 1];
    if (i < 250) {
        for (int k = 0; k < 80; ++k) {
            row[i * 80 + k] = run;
            run += cnt[i * 80 + k];
        }
    }
}

__global__ void k_scatter(const int* __restrict__ iout,
                          const unsigned* __restrict__ row,
                          unsigned* __restrict__ cur,
                          unsigned* __restrict__ perm) {
    int t = blockIdx.x * 256 + threadIdx.x;
    int io = iout[t];
    unsigned pos = row[io] + atomicAdd(&cur[io], 1u);
    perm[pos] = (unsigned)t;
}

__global__ void k_mat(const unsigned* __restrict__ perm,
                      const int* __restrict__ iout, const int* __restrict__ iin,
                      const float* __restrict__ Jm,
                      int* __restrict__ sout, int* __restrict__ sin,
                      float* __restrict__ sJ) {
    int t = blockIdx.x * 256 + threadIdx.x;
    unsigned e = perm[t];
    sout[t] = iout[e];
    sin[t]  = iin[e];
#pragma unroll
    for (int b = 0; b < NBATCH; ++b)
        sJ[(size_t)b * EE + t] = Jm[(size_t)b * EE + e];
}

// ===========================================================================
// prep: A-fragment images for ALL THREE MLP layers (r12-verified maps).
// ===========================================================================
__global__ void k_wfrag(const float* __restrict__ W1, const float* __restrict__ W2,
                        const float* __restrict__ W3,
                        unsigned short* __restrict__ af1,
                        unsigned short* __restrict__ af2,
                        unsigned short* __restrict__ af3) {
    int t = blockIdx.x * 256 + threadIdx.x;
    if (t < 2048) {
        int j  = t & 7;
        int l  = (t >> 3) & 63;
        int qt = t >> 9;
        int g  = l >> 4;
        int q  = qt * 16 + (l & 15);
        float base = (j < 7) ? W1[j * 64 + q] : (W1[7 * 64 + q] - W1[8 * 64 + q]);
        unsigned short w0 = bf16bits(base);
        af1[t] = (g < 2) ? w0 : bf16bits(base - bf16tof(w0));
    }
    if (t < 4096) {
        int j  = t & 7;
        int l  = (t >> 3) & 63;
        int kt = (t >> 9) & 1;
        int qt = t >> 10;
        int g  = l >> 4;
        int p  = l & 15;
        int nk = (j >> 1) * 16 + 4 * g + 2 * kt + (j & 1);
        int no = (qt & 1) * 32 + 8 * (p >> 2) + 4 * (qt >> 1) + (p & 3);
        af2[t] = bf16bits(W2[nk * 64 + no]);
    }
    if (t < 1024) {
        int j  = t & 7;
        int l  = (t >> 3) & 63;
        int kt = t >> 9;
        int i  = l & 15;
        int g3 = l >> 4;
        int n  = kt * 32 + 8 * g3 + j;
        af3[t] = (i < 5) ? bf16bits(W3[n * 5 + i]) : (unsigned short)0;
    }
}

// ===========================================================================
// MFMA message kernel — r12-verified 3-layer matrix-pipe body, with the
// 4 batches processed SEQUENTIALLY per wave (r16):
//   - r13 lesson: parallel batch merge blew VGPR (64->108) and halved
//     occupancy. Here the batch loop is "#pragma unroll 1" and scan+atomics
//     run INSIDE the loop, so per-batch register live-set == r12's.
//   - amortized 4x: sout/sin loads, the 7-shuffle scan-mask chain, wave
//     fixed costs. Wave count 20000 -> 5000.
//   - r15 lesson: occupancy cap at this footprint is ~4 waves/SIMD (unified
//     VGPR+AGPR tier), so the only levers are per-wave work amortization.
// grid: (EE/256) = 1250 blocks x 4 waves; each wave: 64 edges x 4 batches.
// ===========================================================================
__global__ void __launch_bounds__(256, 2) msg_kernel(
    const float* __restrict__ sJ, const float* __restrict__ bnode,
    const int* __restrict__ sin, const int* __restrict__ sout,
    const float* __restrict__ b1,
    const unsigned short* __restrict__ af1,
    const unsigned short* __restrict__ af2,
    const unsigned short* __restrict__ af3,
    const float* __restrict__ b2, const float* __restrict__ b3,
    const float* __restrict__ h1,
    float* __restrict__ sCur)
{
    int wid  = threadIdx.x >> 6;
    int lane = threadIdx.x & 63;
    int g = lane >> 4;
    int c = lane & 15;
    int E0 = blockIdx.x * 256 + wid * 64;
    int e  = E0 + lane;

    int io = sout[e];
    int ii = sin[e];

    // ---- segmented-scan masks + tail (batch-invariant, hoisted — r13-
    //      verified correctness; stored as lane-masks, negligible VGPR) ----
    bool addm[6];
#pragma unroll
    for (int s6 = 0; s6 < 6; ++s6) {
        int off = 1 << s6;
        int ko = __shfl_up(io, off, 64);
        addm[s6] = (lane >= off) && (ko == io);
    }
    int nk = __shfl_down(io, 1, 64);
    bool tail = (lane == 63) || (nk != io);

    const short8* pA1 = (const short8*)af1;
    const short8* pA2 = (const short8*)af2;
    const short8* pA3 = (const short8*)af3;

#pragma unroll 1
    for (int bb = 0; bb < NBATCH; ++bb) {
        size_t hoff = ((size_t)bb * NN + io) * Hd;

        // own-edge features (broadcast sources); feature 7 = jm (folded)
        float xf[8];
#pragma unroll
        for (int i = 0; i < Hd; ++i) xf[i] = h1[hoff + i];
        xf[5] = bnode[bb * NN + ii];
        xf[6] = bnode[bb * NN + io];
        xf[7] = sJ[(size_t)bb * EE + e];

        // ---- layer-1 B fragments: x_hi (trunc) / x_lo (residual, RNE) ----
        uint4v B1l[4];
#pragma unroll
        for (int et = 0; et < 4; ++et) {
            float xe[8];
#pragma unroll
            for (int f = 0; f < 8; ++f) xe[f] = __shfl(xf[f], et * 16 + c, 64);

            uint4v hiP, loP;
#pragma unroll
            for (int j2 = 0; j2 < 4; ++j2) {
                float va = xe[2 * j2], vb = xe[2 * j2 + 1];
                unsigned ta = __float_as_uint(va), tb = __float_as_uint(vb);
                unsigned ha = ta & 0xFFFF0000u, hb = tb & 0xFFFF0000u;
                hiP[j2] = hb | (ta >> 16);
                float ra = va - __uint_as_float(ha);
                float rb = vb - __uint_as_float(hb);
                unsigned pk;
                asm("v_cvt_pk_bf16_f32 %0, %1, %2" : "=v"(pk) : "v"(ra), "v"(rb));
                loP[j2] = pk;
            }
#pragma unroll
            for (int d = 0; d < 4; ++d) B1l[et][d] = (g & 1) ? loP[d] : hiP[d];
        }

        // ---- layer-1 MFMA: 4 qt x 4 et, one K=32 MFMA each, b1 in D-init --
        f32x4 D1[4][4];
#pragma unroll
        for (int qt = 0; qt < 4; ++qt) {
            float4 bb1 = *(const float4*)(b1 + qt * 16 + 4 * g);
            short8 a1f = pA1[qt * 64 + lane];
#pragma unroll
            for (int et = 0; et < 4; ++et) {
                f32x4 dinit = (f32x4){bb1.x, bb1.y, bb1.z, bb1.w};
                D1[qt][et] = __builtin_amdgcn_mfma_f32_16x16x32_bf16(
                    a1f, __builtin_bit_cast(short8, B1l[et]), dinit, 0, 0, 0);
            }
        }

        // ---- handoff: relu(D1) -> layer-2 B fragments (no shuffles) ----
        short8 B2[4][2];
#pragma unroll
        for (int et = 0; et < 4; ++et) {
            uint4v w0, w1;
#pragma unroll
            for (int qt = 0; qt < 4; ++qt) {
                float r0 = fmaxf(D1[qt][et][0], 0.0f);
                float r1 = fmaxf(D1[qt][et][1], 0.0f);
                float r2 = fmaxf(D1[qt][et][2], 0.0f);
                float r3 = fmaxf(D1[qt][et][3], 0.0f);
                unsigned p0, p1;
                asm("v_cvt_pk_bf16_f32 %0, %1, %2" : "=v"(p0) : "v"(r0), "v"(r1));
                asm("v_cvt_pk_bf16_f32 %0, %1, %2" : "=v"(p1) : "v"(r2), "v"(r3));
                w0[qt] = p0;
                w1[qt] = p1;
            }
            B2[et][0] = __builtin_bit_cast(short8, w0);
            B2[et][1] = __builtin_bit_cast(short8, w1);
        }

        // ---- layers 2+3 in qt-pairs {half, half+2}; D3 accumulates ----
        f32x4 D3[4];
#pragma unroll
        for (int et = 0; et < 4; ++et) D3[et] = (f32x4){0.f, 0.f, 0.f, 0.f};

#pragma unroll
        for (int half = 0; half < 2; ++half) {
            float4 ba  = *(const float4*)(b2 + half * 32 + 8 * g);
            float4 bbv = *(const float4*)(b2 + half * 32 + 8 * g + 4);
            f32x4 D2a[4], D2b[4];
#pragma unroll
            for (int et = 0; et < 4; ++et) {
                D2a[et] = (f32x4){ba.x, ba.y, ba.z, ba.w};
                D2b[et] = (f32x4){bbv.x, bbv.y, bbv.z, bbv.w};
            }
#pragma unroll
            for (int kt2 = 0; kt2 < 2; ++kt2) {
                short8 a0a = pA2[(half * 2 + kt2) * 64 + lane];
                short8 a0b = pA2[((half + 2) * 2 + kt2) * 64 + lane];
#pragma unroll
                for (int et = 0; et < 4; ++et) {
                    D2a[et] = __builtin_amdgcn_mfma_f32_16x16x32_bf16(a0a, B2[et][kt2], D2a[et], 0, 0, 0);
                    D2b[et] = __builtin_amdgcn_mfma_f32_16x16x32_bf16(a0b, B2[et][kt2], D2b[et], 0, 0, 0);
                }
            }
            short8 a3 = pA3[half * 64 + lane];
#pragma unroll
            for (int et = 0; et < 4; ++et) {
                float x0 = fmaxf(D2a[et][0], 0.0f), x1 = fmaxf(D2a[et][1], 0.0f);
                float x2 = fmaxf(D2a[et][2], 0.0f), x3 = fmaxf(D2a[et][3], 0.0f);
                float y0 = fmaxf(D2b[et][0], 0.0f), y1 = fmaxf(D2b[et][1], 0.0f);
                float y2 = fmaxf(D2b[et][2], 0.0f), y3 = fmaxf(D2b[et][3], 0.0f);
                uint4v pk;
                unsigned p0, p1, p2, p3;
                asm("v_cvt_pk_bf16_f32 %0, %1, %2" : "=v"(p0) : "v"(x0), "v"(x1));
                asm("v_cvt_pk_bf16_f32 %0, %1, %2" : "=v"(p1) : "v"(x2), "v"(x3));
                asm("v_cvt_pk_bf16_f32 %0, %1, %2" : "=v"(p2) : "v"(y0), "v"(y1));
                asm("v_cvt_pk_bf16_f32 %0, %1, %2" : "=v"(p3) : "v"(y2), "v"(y3));
                pk[0] = p0; pk[1] = p1; pk[2] = p2; pk[3] = p3;
                D3[et] = __builtin_amdgcn_mfma_f32_16x16x32_bf16(
                    a3, __builtin_bit_cast(short8, pk), D3[et], 0, 0, 0);
            }
        }

        // ---- redistribution: edge g*16+c <- rows 0-3 @ lane c, row 4 @ 16+c
        float m[Hd];
#pragma unroll
        for (int i = 0; i < 4; ++i) {
            float p0 = __shfl(D3[0][i], c, 64);
            float p1 = __shfl(D3[1][i], c, 64);
            float p2 = __shfl(D3[2][i], c, 64);
            float p3 = __shfl(D3[3][i], c, 64);
            m[i] = ((g == 0) ? p0 : (g == 1) ? p1 : (g == 2) ? p2 : p3) + b3[i];
        }
        {
            float p0 = __shfl(D3[0][0], 16 + c, 64);
            float p1 = __shfl(D3[1][0], 16 + c, 64);
            float p2 = __shfl(D3[2][0], 16 + c, 64);
            float p3 = __shfl(D3[3][0], 16 + c, 64);
            m[4] = ((g == 0) ? p0 : (g == 1) ? p1 : (g == 2) ? p2 : p3) + b3[4];
        }

        // ---- wave segmented sum over sorted keys (masks hoisted) ----
#pragma unroll
        for (int s6 = 0; s6 < 6; ++s6) {
            int off = 1 << s6;
#pragma unroll
            for (int i = 0; i < Hd; ++i) {
                float u = __shfl_up(m[i], off, 64);
                if (addm[s6]) m[i] += u;
            }
        }
        if (tail) {
#pragma unroll
            for (int i = 0; i < Hd; ++i) atomicAdd(&sCur[hoff + i], m[i]);
        }
    }
}

// ---------------------------------------------------------------------------
// per-node GRU update (unchanged, verified).
// ---------------------------------------------------------------------------
__global__ void node_kernel(
    const float* __restrict__ gzW, const float* __restrict__ gzb,
    const float* __restrict__ grW, const float* __restrict__ grb,
    const float* __restrict__ ghW, const float* __restrict__ ghb,
    float* __restrict__ h1, float* __restrict__ m0,
    float* __restrict__ s0buf, const float* __restrict__ s1buf,
    int zeroPrev)
{
    int t = blockIdx.x * 256 + threadIdx.x;
    if (t >= NBATCH * NN) return;
    size_t off = (size_t)t * Hd;

    float h1v[Hd], m0v[Hd], m1v[Hd];
#pragma unroll
    for (int i = 0; i < Hd; ++i) {
        h1v[i] = h1[off + i];
        float m0n = m0[off + i] + s0buf[off + i];
        m0v[i] = m0n;
        m1v[i] = m0n + s1buf[off + i];
        m0[off + i] = m0n;
        if (zeroPrev) s0buf[off + i] = 0.0f;
    }

    float a[15];
#pragma unroll
    for (int i = 0; i < Hd; ++i) { a[i] = h1v[i]; a[5 + i] = m0v[i]; a[10 + i] = m1v[i]; }

    float z[Hd], r[Hd];
#pragma unroll
    for (int i = 0; i < Hd; ++i) {
        float tz = gzb[i], tr = grb[i];
#pragma unroll
        for (int j = 0; j < 15; ++j) {
            tz = fmaf(a[j], gzW[j * Hd + i], tz);
            tr = fmaf(a[j], grW[j * Hd + i], tr);
        }
        z[i] = sigmoidf_(tz);
        r[i] = sigmoidf_(tr);
    }

    float joined[15];
#pragma unroll
    for (int i = 0; i < Hd; ++i) { joined[i] = r[i] * h1v[i]; joined[5 + i] = m0v[i]; joined[10 + i] = m1v[i]; }

#pragma unroll
    for (int i = 0; i < Hd; ++i) {
        float th = ghb[i];
#pragma unroll
        for (int j = 0; j < 15; ++j) th = fmaf(joined[j], ghW[j * Hd + i], th);
        float hh = tanhf(th);
        h1[off + i] = (1.0f - z[i]) * h1v[i] + z[i] * hh;
    }
}

// ---------------------------------------------------------------------------
// output MLP (unchanged, verified; runs once)
// ---------------------------------------------------------------------------
__global__ void __launch_bounds__(256, 1) out_kernel(
    const float* __restrict__ bnode, const float* __restrict__ h1,
    const float* __restrict__ oW1, const float* __restrict__ ob1,
    const float* __restrict__ oW2, const float* __restrict__ ob2,
    const float* __restrict__ oW3, const float* __restrict__ ob3,
    float* __restrict__ out)
{
    int t = blockIdx.x * 256 + threadIdx.x;
    if (t >= NBATCH * NN) return;

    float x[6];
#pragma unroll
    for (int i = 0; i < Hd; ++i) x[i] = h1[(size_t)t * Hd + i];
    x[5] = bnode[t];

    float acc[64];
#pragma unroll
    for (int q = 0; q < 64; ++q) acc[q] = ob2[q];

#pragma unroll 2
    for (int j = 0; j < 64; ++j) {
        float v = ob1[j];
#pragma unroll
        for (int f = 0; f < 6; ++f) v = fmaf(x[f], oW1[f * 64 + j], v);
        v = fmaxf(v, 0.0f);
        const float* __restrict__ w2r = oW2 + j * 64;
#pragma unroll
        for (int q = 0; q < 64; ++q) acc[q] = fmaf(v, w2r[q], acc[q]);
    }

    float o = ob3[0];
#pragma unroll
    for (int q = 0; q < 64; ++q) o = fmaf(fmaxf(acc[q], 0.0f), oW3[q], o);
    out[t] = sigmoidf_(o);
}

// ---------------------------------------------------------------------------
extern "C" void kernel_launch(void* const* d_in, const int* in_sizes, int n_in,
                              void* d_out, int out_size, void* d_ws, size_t ws_size,
                              hipStream_t stream) {
    const float* Jm    = (const float*)d_in[0];
    const float* bnode = (const float*)d_in[1];
    const int*   iin   = (const int*)d_in[2];
    const int*   iout  = (const int*)d_in[3];
    const float* mW1 = (const float*)d_in[4];
    const float* mb1 = (const float*)d_in[5];
    const float* mW2 = (const float*)d_in[6];
    const float* mb2 = (const float*)d_in[7];
    const float* mW3 = (const float*)d_in[8];
    const float* mb3 = (const float*)d_in[9];
    const float* gzW = (const float*)d_in[10];
    const float* gzb = (const float*)d_in[11];
    const float* grW = (const float*)d_in[12];
    const float* grb = (const float*)d_in[13];
    const float* ghW = (const float*)d_in[14];
    const float* ghb = (const float*)d_in[15];
    const float* oW1 = (const float*)d_in[16];
    const float* ob1 = (const float*)d_in[17];
    const float* oW2 = (const float*)d_in[18];
    const float* ob2 = (const float*)d_in[19];
    const float* oW3 = (const float*)d_in[20];
    const float* ob3 = (const float*)d_in[21];

    float* ws = (float*)d_ws;
    float* h1 = ws;
    float* m0 = ws + (size_t)BNH;
    float* sA = ws + (size_t)2 * BNH;
    float* sB = ws + (size_t)3 * BNH;
    unsigned* cnt  = (unsigned*)(ws + (size_t)4 * BNH);
    unsigned* cur  = cnt + NN;
    unsigned* row  = cur + NN;
    unsigned* perm = row + NN;
    int*      sout = (int*)(perm + EE);
    int*      sin  = sout + EE;
    float*    sJ   = (float*)(sin + EE);           // NBATCH*EE floats
    unsigned short* af1 = (unsigned short*)(sJ + (size_t)NBATCH * EE);  // 2048
    unsigned short* af2 = af1 + 2048;                                   // 4096
    unsigned short* af3 = af2 + 4096;                                   // 1024

    // zero h1, m0, sA, sB, cnt, cur (contiguous)
    hipMemsetAsync(d_ws, 0, ((size_t)4 * BNH + 2 * NN) * sizeof(float), stream);

    // one-time (per launch): sort edges by index_out + build weight frag images
    k_hist<<<EE / 256, 256, 0, stream>>>(iout, cnt);
    k_scan<<<1, 256, 0, stream>>>(cnt, row);
    k_scatter<<<EE / 256, 256, 0, stream>>>(iout, row, cur, perm);
    k_mat<<<EE / 256, 256, 0, stream>>>(perm, iout, iin, Jm, sout, sin, sJ);
    k_wfrag<<<20, 256, 0, stream>>>(mW1, mW2, mW3, af1, af2, af3);

    int mgrid = EE / 256;   // 1250 blocks x 4 waves; batches looped per wave
    int ngrid = (NBATCH * NN + 255) / 256;

    float* buf[2] = { sA, sB };
    for (int s = 0; s < 10; ++s) {
        float* sCur  = buf[s & 1];
        float* sPrev = (s == 0) ? sCur : buf[(s + 1) & 1];
        msg_kernel<<<mgrid, 256, 0, stream>>>(sJ, bnode, sin, sout,
                                              mb1, af1, af2, af3,
                                              mb2, mb3, h1, sCur);
        node_kernel<<<ngrid, 256, 0, stream>>>(gzW, gzb, grW, grb, ghW, ghb,
                                               h1, m0, sPrev, sCur,
                                               (s == 0) ? 0 : 1);
    }

    out_kernel<<<ngrid, 256, 0, stream>>>(bnode, h1,
                                          oW1, ob1, oW2, ob2, oW3, ob3,
                                          (float*)d_out);
}

// Round 17
// 532.329 us; speedup vs baseline: 6.1680x; 1.0722x over previous
//
#include <hip/hip_runtime.h>
#include <hip/hip_bf16.h>
#include <math.h>

#define Hd 5
#define NN 20000
#define EE 320000
#define NBATCH 4
#define BNH (NBATCH * NN * Hd) /* 400000 */

typedef __attribute__((ext_vector_type(8))) short short8;
typedef __attribute__((ext_vector_type(4))) float f32x4;
typedef __attribute__((ext_vector_type(4))) unsigned int uint4v;

__device__ __forceinline__ float sigmoidf_(float v) {
    return 1.0f / (1.0f + expf(-v));
}

__device__ __forceinline__ unsigned short bf16bits(float v) {
    __hip_bfloat16 h = __float2bfloat16(v);
    return *(unsigned short*)&h;
}
__device__ __forceinline__ float bf16tof(unsigned short u) {
    __hip_bfloat16 h = *(__hip_bfloat16*)&u;
    return __bfloat162float(h);
}

// ===========================================================================
// one-time per-launch edge sort by index_out (counting sort) — verified r4/r5
// ===========================================================================
__global__ void k_hist(const int* __restrict__ iout, unsigned* __restrict__ cnt) {
    int t = blockIdx.x * 256 + threadIdx.x;
    atomicAdd(&cnt[iout[t]], 1u);
}

__global__ void k_scan(const unsigned* __restrict__ cnt, unsigned* __restrict__ row) {
    __shared__ unsigned part[256];
    int i = threadIdx.x;
    unsigned s = 0;
    if (i < 250) {
        for (int k = 0; k < 80; ++k) s += cnt[i * 80 + k];
    }
    part[i] = s;
    __syncthreads();
    for (int off = 1; off < 256; off <<= 1) {
        unsigned v = part[i];
        unsigned u = (i >= off) ? part[i - off] : 0u;
        __syncthreads();
        part[i] = v + u;
        __syncthreads();
    }
    unsigned run = (i == 0) ? 0u : part[i - 1];
    if (i < 250) {
        for (int k = 0; k < 80; ++k) {
            row[i * 80 + k] = run;
            run += cnt[i * 80 + k];
        }
    }
}

__global__ void k_scatter(const int* __restrict__ iout,
                          const unsigned* __restrict__ row,
                          unsigned* __restrict__ cur,
                          unsigned* __restrict__ perm) {
    int t = blockIdx.x * 256 + threadIdx.x;
    int io = iout[t];
    unsigned pos = row[io] + atomicAdd(&cur[io], 1u);
    perm[pos] = (unsigned)t;
}

__global__ void k_mat(const unsigned* __restrict__ perm,
                      const int* __restrict__ iout, const int* __restrict__ iin,
                      const float* __restrict__ Jm,
                      int* __restrict__ sout, int* __restrict__ sin,
                      float* __restrict__ sJ) {
    int t = blockIdx.x * 256 + threadIdx.x;
    unsigned e = perm[t];
    sout[t] = iout[e];
    sin[t]  = iin[e];
#pragma unroll
    for (int b = 0; b < NBATCH; ++b)
        sJ[(size_t)b * EE + t] = Jm[(size_t)b * EE + e];
}

// ===========================================================================
// prep: A-fragment images for ALL THREE MLP layers (r12-verified maps).
// ===========================================================================
__global__ void k_wfrag(const float* __restrict__ W1, const float* __restrict__ W2,
                        const float* __restrict__ W3,
                        unsigned short* __restrict__ af1,
                        unsigned short* __restrict__ af2,
                        unsigned short* __restrict__ af3) {
    int t = blockIdx.x * 256 + threadIdx.x;
    if (t < 2048) {
        int j  = t & 7;
        int l  = (t >> 3) & 63;
        int qt = t >> 9;
        int g  = l >> 4;
        int q  = qt * 16 + (l & 15);
        float base = (j < 7) ? W1[j * 64 + q] : (W1[7 * 64 + q] - W1[8 * 64 + q]);
        unsigned short w0 = bf16bits(base);
        af1[t] = (g < 2) ? w0 : bf16bits(base - bf16tof(w0));
    }
    if (t < 4096) {
        int j  = t & 7;
        int l  = (t >> 3) & 63;
        int kt = (t >> 9) & 1;
        int qt = t >> 10;
        int g  = l >> 4;
        int p  = l & 15;
        int nk = (j >> 1) * 16 + 4 * g + 2 * kt + (j & 1);
        int no = (qt & 1) * 32 + 8 * (p >> 2) + 4 * (qt >> 1) + (p & 3);
        af2[t] = bf16bits(W2[nk * 64 + no]);
    }
    if (t < 1024) {
        int j  = t & 7;
        int l  = (t >> 3) & 63;
        int kt = t >> 9;
        int i  = l & 15;
        int g3 = l >> 4;
        int n  = kt * 32 + 8 * g3 + j;
        af3[t] = (i < 5) ? bf16bits(W3[n * 5 + i]) : (unsigned short)0;
    }
}

// ===========================================================================
// MFMA message kernel — r12-verified arithmetic, RE-SCHEDULED for minimal
// peak register live-set (r17):
//   r15 diagnosis: residency cap = exactly 4 waves/SIMD at "VGPR 64" -> the
//   unified-file total (arch+accum) is ~128. r12 held D1[4][4] (64 regs)
//   live across the whole layer-1 block.
//   (a) layer-1 MFMA + handoff fused PER-QT: D1 live 64 -> 16
//   (b) layers 2+3 run PER-ET: D2a/D2b live 32 -> 8
//   (c) __launch_bounds__(256,5): cap 102 regs -> 5 waves/SIMD (+25% res.)
// Values computed are IDENTICAL to r12 (same MFMAs/operands, new order).
// grid: (EE/256, NBATCH), block 256 (4 waves), no LDS.
// ===========================================================================
__global__ void __launch_bounds__(256, 5) msg_kernel(
    const float* __restrict__ sJ, const float* __restrict__ bnode,
    const int* __restrict__ sin, const int* __restrict__ sout,
    const float* __restrict__ b1,
    const unsigned short* __restrict__ af1,
    const unsigned short* __restrict__ af2,
    const unsigned short* __restrict__ af3,
    const float* __restrict__ b2, const float* __restrict__ b3,
    const float* __restrict__ h1,
    float* __restrict__ sCur)
{
    int wid  = threadIdx.x >> 6;
    int lane = threadIdx.x & 63;
    int g = lane >> 4;
    int c = lane & 15;
    int E0 = blockIdx.x * 256 + wid * 64;
    int bb = blockIdx.y;
    int e  = E0 + lane;

    int io = sout[e];
    int ii = sin[e];
    size_t hoff = ((size_t)bb * NN + io) * Hd;

    // own-edge features (broadcast sources); feature 7 = jm (weight folded)
    float xf[8];
#pragma unroll
    for (int i = 0; i < Hd; ++i) xf[i] = h1[hoff + i];
    xf[5] = bnode[bb * NN + ii];
    xf[6] = bnode[bb * NN + io];
    xf[7] = sJ[(size_t)bb * EE + e];

    // ---- build layer-1 B fragments: x_hi (trunc) / x_lo (residual, RNE) ----
    uint4v B1l[4];
#pragma unroll
    for (int et = 0; et < 4; ++et) {
        float xe[8];
#pragma unroll
        for (int f = 0; f < 8; ++f) xe[f] = __shfl(xf[f], et * 16 + c, 64);

        uint4v hiP, loP;
#pragma unroll
        for (int j2 = 0; j2 < 4; ++j2) {
            float va = xe[2 * j2], vb = xe[2 * j2 + 1];
            unsigned ta = __float_as_uint(va), tb = __float_as_uint(vb);
            unsigned ha = ta & 0xFFFF0000u, hb = tb & 0xFFFF0000u;
            hiP[j2] = hb | (ta >> 16);
            float ra = va - __uint_as_float(ha);
            float rb = vb - __uint_as_float(hb);
            unsigned pk;
            asm("v_cvt_pk_bf16_f32 %0, %1, %2" : "=v"(pk) : "v"(ra), "v"(rb));
            loP[j2] = pk;
        }
#pragma unroll
        for (int d = 0; d < 4; ++d) B1l[et][d] = (g & 1) ? loP[d] : hiP[d];
    }

    // ---- layer-1 MFMA fused with handoff, per qt (D1 live-set = 16) ----
    // B2 dwords: B2w0[et][qt] = pk(relu(D1[qt][et][0]), relu(D1[qt][et][1]))
    //            B2w1[et][qt] = pk(relu(D1[qt][et][2]), relu(D1[qt][et][3]))
    const short8* pA1 = (const short8*)af1;
    uint4v B2w0[4], B2w1[4];
#pragma unroll
    for (int qt = 0; qt < 4; ++qt) {
        float4 bb1 = *(const float4*)(b1 + qt * 16 + 4 * g);
        short8 a1f = pA1[qt * 64 + lane];
#pragma unroll
        for (int et = 0; et < 4; ++et) {
            f32x4 dinit = (f32x4){bb1.x, bb1.y, bb1.z, bb1.w};
            f32x4 d = __builtin_amdgcn_mfma_f32_16x16x32_bf16(
                a1f, __builtin_bit_cast(short8, B1l[et]), dinit, 0, 0, 0);
            float r0 = fmaxf(d[0], 0.0f);
            float r1 = fmaxf(d[1], 0.0f);
            float r2 = fmaxf(d[2], 0.0f);
            float r3 = fmaxf(d[3], 0.0f);
            unsigned p0, p1;
            asm("v_cvt_pk_bf16_f32 %0, %1, %2" : "=v"(p0) : "v"(r0), "v"(r1));
            asm("v_cvt_pk_bf16_f32 %0, %1, %2" : "=v"(p1) : "v"(r2), "v"(r3));
            B2w0[et][qt] = p0;
            B2w1[et][qt] = p1;
        }
    }

    // ---- layers 2+3 per half, per et (D2 live-set = 8); D3 accumulates ----
    const short8* pA2 = (const short8*)af2;
    const short8* pA3 = (const short8*)af3;

    f32x4 D3[4];
#pragma unroll
    for (int et = 0; et < 4; ++et) D3[et] = (f32x4){0.f, 0.f, 0.f, 0.f};

#pragma unroll
    for (int half = 0; half < 2; ++half) {
        float4 ba  = *(const float4*)(b2 + half * 32 + 8 * g);
        float4 bbv = *(const float4*)(b2 + half * 32 + 8 * g + 4);
        short8 a0a0 = pA2[(half * 2 + 0) * 64 + lane];
        short8 a0a1 = pA2[(half * 2 + 1) * 64 + lane];
        short8 a0b0 = pA2[((half + 2) * 2 + 0) * 64 + lane];
        short8 a0b1 = pA2[((half + 2) * 2 + 1) * 64 + lane];
        short8 a3   = pA3[half * 64 + lane];
#pragma unroll
        for (int et = 0; et < 4; ++et) {
            short8 b20 = __builtin_bit_cast(short8, B2w0[et]);
            short8 b21 = __builtin_bit_cast(short8, B2w1[et]);
            f32x4 Da = (f32x4){ba.x, ba.y, ba.z, ba.w};
            f32x4 Db = (f32x4){bbv.x, bbv.y, bbv.z, bbv.w};
            Da = __builtin_amdgcn_mfma_f32_16x16x32_bf16(a0a0, b20, Da, 0, 0, 0);
            Da = __builtin_amdgcn_mfma_f32_16x16x32_bf16(a0a1, b21, Da, 0, 0, 0);
            Db = __builtin_amdgcn_mfma_f32_16x16x32_bf16(a0b0, b20, Db, 0, 0, 0);
            Db = __builtin_amdgcn_mfma_f32_16x16x32_bf16(a0b1, b21, Db, 0, 0, 0);

            float x0 = fmaxf(Da[0], 0.0f), x1 = fmaxf(Da[1], 0.0f);
            float x2 = fmaxf(Da[2], 0.0f), x3 = fmaxf(Da[3], 0.0f);
            float y0 = fmaxf(Db[0], 0.0f), y1 = fmaxf(Db[1], 0.0f);
            float y2 = fmaxf(Db[2], 0.0f), y3 = fmaxf(Db[3], 0.0f);
            uint4v pk;
            unsigned p0, p1, p2, p3;
            asm("v_cvt_pk_bf16_f32 %0, %1, %2" : "=v"(p0) : "v"(x0), "v"(x1));
            asm("v_cvt_pk_bf16_f32 %0, %1, %2" : "=v"(p1) : "v"(x2), "v"(x3));
            asm("v_cvt_pk_bf16_f32 %0, %1, %2" : "=v"(p2) : "v"(y0), "v"(y1));
            asm("v_cvt_pk_bf16_f32 %0, %1, %2" : "=v"(p3) : "v"(y2), "v"(y3));
            pk[0] = p0; pk[1] = p1; pk[2] = p2; pk[3] = p3;
            D3[et] = __builtin_amdgcn_mfma_f32_16x16x32_bf16(
                a3, __builtin_bit_cast(short8, pk), D3[et], 0, 0, 0);
        }
    }

    // ---- redistribution: edge g*16+c <- rows 0-3 @ lane c, row 4 @ 16+c ----
    float m[Hd];
#pragma unroll
    for (int i = 0; i < 4; ++i) {
        float p0 = __shfl(D3[0][i], c, 64);
        float p1 = __shfl(D3[1][i], c, 64);
        float p2 = __shfl(D3[2][i], c, 64);
        float p3 = __shfl(D3[3][i], c, 64);
        m[i] = ((g == 0) ? p0 : (g == 1) ? p1 : (g == 2) ? p2 : p3) + b3[i];
    }
    {
        float p0 = __shfl(D3[0][0], 16 + c, 64);
        float p1 = __shfl(D3[1][0], 16 + c, 64);
        float p2 = __shfl(D3[2][0], 16 + c, 64);
        float p3 = __shfl(D3[3][0], 16 + c, 64);
        m[4] = ((g == 0) ? p0 : (g == 1) ? p1 : (g == 2) ? p2 : p3) + b3[4];
    }

    // ---- wave segmented sum over sorted keys (verified round-5 code) ----
#pragma unroll
    for (int off = 1; off < 64; off <<= 1) {
        int ko = __shfl_up(io, off, 64);
        bool add = (lane >= off) && (ko == io);
#pragma unroll
        for (int i = 0; i < Hd; ++i) {
            float u = __shfl_up(m[i], off, 64);
            if (add) m[i] += u;
        }
    }
    int nk = __shfl_down(io, 1, 64);
    bool tail = (lane == 63) || (nk != io);
    if (tail) {
#pragma unroll
        for (int i = 0; i < Hd; ++i) atomicAdd(&sCur[hoff + i], m[i]);
    }
}

// ---------------------------------------------------------------------------
// per-node GRU update (unchanged, verified).
// ---------------------------------------------------------------------------
__global__ void node_kernel(
    const float* __restrict__ gzW, const float* __restrict__ gzb,
    const float* __restrict__ grW, const float* __restrict__ grb,
    const float* __restrict__ ghW, const float* __restrict__ ghb,
    float* __restrict__ h1, float* __restrict__ m0,
    float* __restrict__ s0buf, const float* __restrict__ s1buf,
    int zeroPrev)
{
    int t = blockIdx.x * 256 + threadIdx.x;
    if (t >= NBATCH * NN) return;
    size_t off = (size_t)t * Hd;

    float h1v[Hd], m0v[Hd], m1v[Hd];
#pragma unroll
    for (int i = 0; i < Hd; ++i) {
        h1v[i] = h1[off + i];
        float m0n = m0[off + i] + s0buf[off + i];
        m0v[i] = m0n;
        m1v[i] = m0n + s1buf[off + i];
        m0[off + i] = m0n;
        if (zeroPrev) s0buf[off + i] = 0.0f;
    }

    float a[15];
#pragma unroll
    for (int i = 0; i < Hd; ++i) { a[i] = h1v[i]; a[5 + i] = m0v[i]; a[10 + i] = m1v[i]; }

    float z[Hd], r[Hd];
#pragma unroll
    for (int i = 0; i < Hd; ++i) {
        float tz = gzb[i], tr = grb[i];
#pragma unroll
        for (int j = 0; j < 15; ++j) {
            tz = fmaf(a[j], gzW[j * Hd + i], tz);
            tr = fmaf(a[j], grW[j * Hd + i], tr);
        }
        z[i] = sigmoidf_(tz);
        r[i] = sigmoidf_(tr);
    }

    float joined[15];
#pragma unroll
    for (int i = 0; i < Hd; ++i) { joined[i] = r[i] * h1v[i]; joined[5 + i] = m0v[i]; joined[10 + i] = m1v[i]; }

#pragma unroll
    for (int i = 0; i < Hd; ++i) {
        float th = ghb[i];
#pragma unroll
        for (int j = 0; j < 15; ++j) th = fmaf(joined[j], ghW[j * Hd + i], th);
        float hh = tanhf(th);
        h1[off + i] = (1.0f - z[i]) * h1v[i] + z[i] * hh;
    }
}

// ---------------------------------------------------------------------------
// output MLP (unchanged, verified; runs once)
// ---------------------------------------------------------------------------
__global__ void __launch_bounds__(256, 1) out_kernel(
    const float* __restrict__ bnode, const float* __restrict__ h1,
    const float* __restrict__ oW1, const float* __restrict__ ob1,
    const float* __restrict__ oW2, const float* __restrict__ ob2,
    const float* __restrict__ oW3, const float* __restrict__ ob3,
    float* __restrict__ out)
{
    int t = blockIdx.x * 256 + threadIdx.x;
    if (t >= NBATCH * NN) return;

    float x[6];
#pragma unroll
    for (int i = 0; i < Hd; ++i) x[i] = h1[(size_t)t * Hd + i];
    x[5] = bnode[t];

    float acc[64];
#pragma unroll
    for (int q = 0; q < 64; ++q) acc[q] = ob2[q];

#pragma unroll 2
    for (int j = 0; j < 64; ++j) {
        float v = ob1[j];
#pragma unroll
        for (int f = 0; f < 6; ++f) v = fmaf(x[f], oW1[f * 64 + j], v);
        v = fmaxf(v, 0.0f);
        const float* __restrict__ w2r = oW2 + j * 64;
#pragma unroll
        for (int q = 0; q < 64; ++q) acc[q] = fmaf(v, w2r[q], acc[q]);
    }

    float o = ob3[0];
#pragma unroll
    for (int q = 0; q < 64; ++q) o = fmaf(fmaxf(acc[q], 0.0f), oW3[q], o);
    out[t] = sigmoidf_(o);
}

// ---------------------------------------------------------------------------
extern "C" void kernel_launch(void* const* d_in, const int* in_sizes, int n_in,
                              void* d_out, int out_size, void* d_ws, size_t ws_size,
                              hipStream_t stream) {
    const float* Jm    = (const float*)d_in[0];
    const float* bnode = (const float*)d_in[1];
    const int*   iin   = (const int*)d_in[2];
    const int*   iout  = (const int*)d_in[3];
    const float* mW1 = (const float*)d_in[4];
    const float* mb1 = (const float*)d_in[5];
    const float* mW2 = (const float*)d_in[6];
    const float* mb2 = (const float*)d_in[7];
    const float* mW3 = (const float*)d_in[8];
    const float* mb3 = (const float*)d_in[9];
    const float* gzW = (const float*)d_in[10];
    const float* gzb = (const float*)d_in[11];
    const float* grW = (const float*)d_in[12];
    const float* grb = (const float*)d_in[13];
    const float* ghW = (const float*)d_in[14];
    const float* ghb = (const float*)d_in[15];
    const float* oW1 = (const float*)d_in[16];
    const float* ob1 = (const float*)d_in[17];
    const float* oW2 = (const float*)d_in[18];
    const float* ob2 = (const float*)d_in[19];
    const float* oW3 = (const float*)d_in[20];
    const float* ob3 = (const float*)d_in[21];

    float* ws = (float*)d_ws;
    float* h1 = ws;
    float* m0 = ws + (size_t)BNH;
    float* sA = ws + (size_t)2 * BNH;
    float* sB = ws + (size_t)3 * BNH;
    unsigned* cnt  = (unsigned*)(ws + (size_t)4 * BNH);
    unsigned* cur  = cnt + NN;
    unsigned* row  = cur + NN;
    unsigned* perm = row + NN;
    int*      sout = (int*)(perm + EE);
    int*      sin  = sout + EE;
    float*    sJ   = (float*)(sin + EE);           // NBATCH*EE floats
    unsigned short* af1 = (unsigned short*)(sJ + (size_t)NBATCH * EE);  // 2048
    unsigned short* af2 = af1 + 2048;                                   // 4096
    unsigned short* af3 = af2 + 4096;                                   // 1024

    // zero h1, m0, sA, sB, cnt, cur (contiguous)
    hipMemsetAsync(d_ws, 0, ((size_t)4 * BNH + 2 * NN) * sizeof(float), stream);

    // one-time (per launch): sort edges by index_out + build weight frag images
    k_hist<<<EE / 256, 256, 0, stream>>>(iout, cnt);
    k_scan<<<1, 256, 0, stream>>>(cnt, row);
    k_scatter<<<EE / 256, 256, 0, stream>>>(iout, row, cur, perm);
    k_mat<<<EE / 256, 256, 0, stream>>>(perm, iout, iin, Jm, sout, sin, sJ);
    k_wfrag<<<20, 256, 0, stream>>>(mW1, mW2, mW3, af1, af2, af3);

    dim3 mgrid(EE / 256, NBATCH);
    int ngrid = (NBATCH * NN + 255) / 256;

    float* buf[2] = { sA, sB };
    for (int s = 0; s < 10; ++s) {
        float* sCur  = buf[s & 1];
        float* sPrev = (s == 0) ? sCur : buf[(s + 1) & 1];
        msg_kernel<<<mgrid, 256, 0, stream>>>(sJ, bnode, sin, sout,
                                              mb1, af1, af2, af3,
                                              mb2, mb3, h1, sCur);
        node_kernel<<<ngrid, 256, 0, stream>>>(gzW, gzb, grW, grb, ghW, ghb,
                                               h1, m0, sPrev, sCur,
                                               (s == 0) ? 0 : 1);
    }

    out_kernel<<<ngrid, 256, 0, stream>>>(bnode, h1,
                                          oW1, ob1, oW2, ob2, oW3, ob3,
                                          (float*)d_out);
}

// Round 18
// 513.350 us; speedup vs baseline: 6.3960x; 1.0370x over previous
//
#include <hip/hip_runtime.h>
#include <hip/hip_bf16.h>
#include <math.h>

#define Hd 5
#define NN 20000
#define EE 320000
#define NBATCH 4
#define BNH (NBATCH * NN * Hd) /* 400000 */

typedef __attribute__((ext_vector_type(8))) short short8;
typedef __attribute__((ext_vector_type(4))) float f32x4;
typedef __attribute__((ext_vector_type(4))) unsigned int uint4v;

__device__ __forceinline__ float sigmoidf_(float v) {
    return 1.0f / (1.0f + expf(-v));
}

__device__ __forceinline__ unsigned short bf16bits(float v) {
    __hip_bfloat16 h = __float2bfloat16(v);
    return *(unsigned short*)&h;
}
__device__ __forceinline__ float bf16tof(unsigned short u) {
    __hip_bfloat16 h = *(__hip_bfloat16*)&u;
    return __bfloat162float(h);
}

// ===========================================================================
// one-time per-launch edge sort by index_out (counting sort) — verified r4/r5
// ===========================================================================
__global__ void k_hist(const int* __restrict__ iout, unsigned* __restrict__ cnt) {
    int t = blockIdx.x * 256 + threadIdx.x;
    atomicAdd(&cnt[iout[t]], 1u);
}

__global__ void k_scan(const unsigned* __restrict__ cnt, unsigned* __restrict__ row) {
    __shared__ unsigned part[256];
    int i = threadIdx.x;
    unsigned s = 0;
    if (i < 250) {
        for (int k = 0; k < 80; ++k) s += cnt[i * 80 + k];
    }
    part[i] = s;
    __syncthreads();
    for (int off = 1; off < 256; off <<= 1) {
        unsigned v = part[i];
        unsigned u = (i >= off) ? part[i - off] : 0u;
        __syncthreads();
        part[i] = v + u;
        __syncthreads();
    }
    unsigned run = (i == 0) ? 0u : part[i - 1];
    if (i < 250) {
        for (int k = 0; k < 80; ++k) {
            row[i * 80 + k] = run;
            run += cnt[i * 80 + k];
        }
    }
}

__global__ void k_scatter(const int* __restrict__ iout,
                          const unsigned* __restrict__ row,
                          unsigned* __restrict__ cur,
                          unsigned* __restrict__ perm) {
    int t = blockIdx.x * 256 + threadIdx.x;
    int io = iout[t];
    unsigned pos = row[io] + atomicAdd(&cur[io], 1u);
    perm[pos] = (unsigned)t;
}

__global__ void k_mat(const unsigned* __restrict__ perm,
                      const int* __restrict__ iout, const int* __restrict__ iin,
                      const float* __restrict__ Jm,
                      int* __restrict__ sout, int* __restrict__ sin,
                      float* __restrict__ sJ) {
    int t = blockIdx.x * 256 + threadIdx.x;
    unsigned e = perm[t];
    sout[t] = iout[e];
    sin[t]  = iin[e];
#pragma unroll
    for (int b = 0; b < NBATCH; ++b)
        sJ[(size_t)b * EE + t] = Jm[(size_t)b * EE + e];
}

// ===========================================================================
// prep: A-fragment images for ALL THREE MLP layers.
// Layer 1 (af1, 2048): K=32 MFMA holds 4-term split (W0+Wr)(x0+x1):
//   slot 8g+j: A = (g<2 ? bf16(W1eff[j][q]) : resid), q=qt*16+(l&15)
//   W1eff[7] = W1[7]-W1[8] (folds -jm).
// Layer 2 (af2, 4096): k-map n_k(kt,g,j) = (j>>1)*16+4g+2kt+(j&1) matches
//   layer-1's D output.  Out-map (free relabeling):
//   n_out(qt,p) = (qt&1)*32 + 8*(p>>2) + 4*(qt>>1) + (p&3), p = D row pos,
//   so D2 rows of qt-pair {kt,kt+2} ARE layer-3 B slots k=kt*32+8g+j.
// Layer 3 (af3, 1024): A row i=(l&15) (out channel, rows 5..15 zero),
//   k-slot (kt,g,j) -> neuron n = kt*32+8g+j (same map as B side).
// ===========================================================================
__global__ void k_wfrag(const float* __restrict__ W1, const float* __restrict__ W2,
                        const float* __restrict__ W3,
                        unsigned short* __restrict__ af1,
                        unsigned short* __restrict__ af2,
                        unsigned short* __restrict__ af3) {
    int t = blockIdx.x * 256 + threadIdx.x;
    if (t < 2048) {
        int j  = t & 7;
        int l  = (t >> 3) & 63;
        int qt = t >> 9;
        int g  = l >> 4;
        int q  = qt * 16 + (l & 15);
        float base = (j < 7) ? W1[j * 64 + q] : (W1[7 * 64 + q] - W1[8 * 64 + q]);
        unsigned short w0 = bf16bits(base);
        af1[t] = (g < 2) ? w0 : bf16bits(base - bf16tof(w0));
    }
    if (t < 4096) {
        int j  = t & 7;
        int l  = (t >> 3) & 63;
        int kt = (t >> 9) & 1;
        int qt = t >> 10;
        int g  = l >> 4;
        int p  = l & 15;
        int nk = (j >> 1) * 16 + 4 * g + 2 * kt + (j & 1);
        int no = (qt & 1) * 32 + 8 * (p >> 2) + 4 * (qt >> 1) + (p & 3);
        af2[t] = bf16bits(W2[nk * 64 + no]);
    }
    if (t < 1024) {
        int j  = t & 7;
        int l  = (t >> 3) & 63;
        int kt = t >> 9;
        int i  = l & 15;
        int g3 = l >> 4;
        int n  = kt * 32 + 8 * g3 + j;
        af3[t] = (i < 5) ? bf16bits(W3[n * 5 + i]) : (unsigned short)0;
    }
}

// ===========================================================================
// MFMA message kernel — ALL THREE layers on the matrix pipe (r12 champion,
// 514 us total). One wave = 64 sorted edges x 1 batch.
// Layer 1: 16 MFMA (4-term split, b1 via D-init) -> handoff (relu+cvt_pk,
//   no shuffles) -> Layer 2: 32 MFMA in qt-pairs {half,half+2} (b2 via
//   D-init at relabeled rows) -> handoff -> Layer 3: 8 MFMA produce
//   Z3[5][64 edges] (K=64 contraction replaces shfl reduce).
// Redistribution: edge g*16+c pulls rows 0-3 from lane c, row 4 from 16+c.
// Scan/atomics: r5-verified segmented sum.
// Ledger (r13-r17): occupancy/ILP/dispatch levers all null or negative;
// practical latency floor of this structure. VALU-issue floor ~20us/disp,
// measured ~45us/disp, gap = per-wave serial chains not hideable at any
// achievable residency.
// grid: (EE/256, NBATCH), block 256 (4 waves), no LDS.
// ===========================================================================
__global__ void __launch_bounds__(256, 2) msg_kernel(
    const float* __restrict__ sJ, const float* __restrict__ bnode,
    const int* __restrict__ sin, const int* __restrict__ sout,
    const float* __restrict__ b1,
    const unsigned short* __restrict__ af1,
    const unsigned short* __restrict__ af2,
    const unsigned short* __restrict__ af3,
    const float* __restrict__ b2, const float* __restrict__ b3,
    const float* __restrict__ h1,
    float* __restrict__ sCur)
{
    int wid  = threadIdx.x >> 6;
    int lane = threadIdx.x & 63;
    int g = lane >> 4;
    int c = lane & 15;
    int E0 = blockIdx.x * 256 + wid * 64;
    int bb = blockIdx.y;
    int e  = E0 + lane;

    int io = sout[e];
    int ii = sin[e];
    size_t hoff = ((size_t)bb * NN + io) * Hd;

    // own-edge features (broadcast sources); feature 7 = jm (weight folded)
    float xf[8];
#pragma unroll
    for (int i = 0; i < Hd; ++i) xf[i] = h1[hoff + i];
    xf[5] = bnode[bb * NN + ii];
    xf[6] = bnode[bb * NN + io];
    xf[7] = sJ[(size_t)bb * EE + e];

    // ---- build layer-1 B fragments: x_hi (trunc) / x_lo (residual, RNE) ----
    uint4v B1l[4];
#pragma unroll
    for (int et = 0; et < 4; ++et) {
        float xe[8];
#pragma unroll
        for (int f = 0; f < 8; ++f) xe[f] = __shfl(xf[f], et * 16 + c, 64);

        uint4v hiP, loP;
#pragma unroll
        for (int j2 = 0; j2 < 4; ++j2) {
            float va = xe[2 * j2], vb = xe[2 * j2 + 1];
            unsigned ta = __float_as_uint(va), tb = __float_as_uint(vb);
            unsigned ha = ta & 0xFFFF0000u, hb = tb & 0xFFFF0000u;
            hiP[j2] = hb | (ta >> 16);
            float ra = va - __uint_as_float(ha);
            float rb = vb - __uint_as_float(hb);
            unsigned pk;
            asm("v_cvt_pk_bf16_f32 %0, %1, %2" : "=v"(pk) : "v"(ra), "v"(rb));
            loP[j2] = pk;
        }
#pragma unroll
        for (int d = 0; d < 4; ++d) B1l[et][d] = (g & 1) ? loP[d] : hiP[d];
    }

    // ---- layer-1 MFMA: 4 qt x 4 et, one K=32 MFMA each, b1 in D-init ----
    const short8* pA1 = (const short8*)af1;
    f32x4 D1[4][4];
#pragma unroll
    for (int qt = 0; qt < 4; ++qt) {
        float4 bb1 = *(const float4*)(b1 + qt * 16 + 4 * g);
        short8 a1f = pA1[qt * 64 + lane];
#pragma unroll
        for (int et = 0; et < 4; ++et) {
            f32x4 dinit = (f32x4){bb1.x, bb1.y, bb1.z, bb1.w};
            D1[qt][et] = __builtin_amdgcn_mfma_f32_16x16x32_bf16(
                a1f, __builtin_bit_cast(short8, B1l[et]), dinit, 0, 0, 0);
        }
    }

    // ---- handoff: relu(D1) -> layer-2 B fragments (no shuffles) ----
    short8 B2[4][2];
#pragma unroll
    for (int et = 0; et < 4; ++et) {
        uint4v w0, w1;
#pragma unroll
        for (int qt = 0; qt < 4; ++qt) {
            float r0 = fmaxf(D1[qt][et][0], 0.0f);
            float r1 = fmaxf(D1[qt][et][1], 0.0f);
            float r2 = fmaxf(D1[qt][et][2], 0.0f);
            float r3 = fmaxf(D1[qt][et][3], 0.0f);
            unsigned p0, p1;
            asm("v_cvt_pk_bf16_f32 %0, %1, %2" : "=v"(p0) : "v"(r0), "v"(r1));
            asm("v_cvt_pk_bf16_f32 %0, %1, %2" : "=v"(p1) : "v"(r2), "v"(r3));
            w0[qt] = p0;
            w1[qt] = p1;
        }
        B2[et][0] = __builtin_bit_cast(short8, w0);
        B2[et][1] = __builtin_bit_cast(short8, w1);
    }

    // ---- layers 2+3 in qt-pairs {half, half+2}; D3 accumulates over half ----
    const short8* pA2 = (const short8*)af2;
    const short8* pA3 = (const short8*)af3;

    f32x4 D3[4];
#pragma unroll
    for (int et = 0; et < 4; ++et) D3[et] = (f32x4){0.f, 0.f, 0.f, 0.f};

#pragma unroll
    for (int half = 0; half < 2; ++half) {
        float4 ba  = *(const float4*)(b2 + half * 32 + 8 * g);
        float4 bbv = *(const float4*)(b2 + half * 32 + 8 * g + 4);
        f32x4 D2a[4], D2b[4];
#pragma unroll
        for (int et = 0; et < 4; ++et) {
            D2a[et] = (f32x4){ba.x, ba.y, ba.z, ba.w};
            D2b[et] = (f32x4){bbv.x, bbv.y, bbv.z, bbv.w};
        }
#pragma unroll
        for (int kt2 = 0; kt2 < 2; ++kt2) {
            short8 a0a = pA2[(half * 2 + kt2) * 64 + lane];
            short8 a0b = pA2[((half + 2) * 2 + kt2) * 64 + lane];
#pragma unroll
            for (int et = 0; et < 4; ++et) {
                D2a[et] = __builtin_amdgcn_mfma_f32_16x16x32_bf16(a0a, B2[et][kt2], D2a[et], 0, 0, 0);
                D2b[et] = __builtin_amdgcn_mfma_f32_16x16x32_bf16(a0b, B2[et][kt2], D2b[et], 0, 0, 0);
            }
        }
        // handoff: relu(D2 pair) -> layer-3 B fragment for k-tile `half`
        short8 a3 = pA3[half * 64 + lane];
#pragma unroll
        for (int et = 0; et < 4; ++et) {
            float x0 = fmaxf(D2a[et][0], 0.0f), x1 = fmaxf(D2a[et][1], 0.0f);
            float x2 = fmaxf(D2a[et][2], 0.0f), x3 = fmaxf(D2a[et][3], 0.0f);
            float y0 = fmaxf(D2b[et][0], 0.0f), y1 = fmaxf(D2b[et][1], 0.0f);
            float y2 = fmaxf(D2b[et][2], 0.0f), y3 = fmaxf(D2b[et][3], 0.0f);
            uint4v pk;
            unsigned p0, p1, p2, p3;
            asm("v_cvt_pk_bf16_f32 %0, %1, %2" : "=v"(p0) : "v"(x0), "v"(x1));
            asm("v_cvt_pk_bf16_f32 %0, %1, %2" : "=v"(p1) : "v"(x2), "v"(x3));
            asm("v_cvt_pk_bf16_f32 %0, %1, %2" : "=v"(p2) : "v"(y0), "v"(y1));
            asm("v_cvt_pk_bf16_f32 %0, %1, %2" : "=v"(p3) : "v"(y2), "v"(y3));
            pk[0] = p0; pk[1] = p1; pk[2] = p2; pk[3] = p3;
            D3[et] = __builtin_amdgcn_mfma_f32_16x16x32_bf16(
                a3, __builtin_bit_cast(short8, pk), D3[et], 0, 0, 0);
        }
    }

    // ---- redistribution: edge g*16+c <- rows 0-3 @ lane c, row 4 @ 16+c ----
    float m[Hd];
#pragma unroll
    for (int i = 0; i < 4; ++i) {
        float p0 = __shfl(D3[0][i], c, 64);
        float p1 = __shfl(D3[1][i], c, 64);
        float p2 = __shfl(D3[2][i], c, 64);
        float p3 = __shfl(D3[3][i], c, 64);
        m[i] = ((g == 0) ? p0 : (g == 1) ? p1 : (g == 2) ? p2 : p3) + b3[i];
    }
    {
        float p0 = __shfl(D3[0][0], 16 + c, 64);
        float p1 = __shfl(D3[1][0], 16 + c, 64);
        float p2 = __shfl(D3[2][0], 16 + c, 64);
        float p3 = __shfl(D3[3][0], 16 + c, 64);
        m[4] = ((g == 0) ? p0 : (g == 1) ? p1 : (g == 2) ? p2 : p3) + b3[4];
    }

    // ---- wave segmented sum over sorted keys (verified round-5 code) ----
#pragma unroll
    for (int off = 1; off < 64; off <<= 1) {
        int ko = __shfl_up(io, off, 64);
        bool add = (lane >= off) && (ko == io);
#pragma unroll
        for (int i = 0; i < Hd; ++i) {
            float u = __shfl_up(m[i], off, 64);
            if (add) m[i] += u;
        }
    }
    int nk = __shfl_down(io, 1, 64);
    bool tail = (lane == 63) || (nk != io);
    if (tail) {
#pragma unroll
        for (int i = 0; i < Hd; ++i) atomicAdd(&sCur[hoff + i], m[i]);
    }
}

// ---------------------------------------------------------------------------
// per-node GRU update (unchanged, verified).
// ---------------------------------------------------------------------------
__global__ void node_kernel(
    const float* __restrict__ gzW, const float* __restrict__ gzb,
    const float* __restrict__ grW, const float* __restrict__ grb,
    const float* __restrict__ ghW, const float* __restrict__ ghb,
    float* __restrict__ h1, float* __restrict__ m0,
    float* __restrict__ s0buf, const float* __restrict__ s1buf,
    int zeroPrev)
{
    int t = blockIdx.x * 256 + threadIdx.x;
    if (t >= NBATCH * NN) return;
    size_t off = (size_t)t * Hd;

    float h1v[Hd], m0v[Hd], m1v[Hd];
#pragma unroll
    for (int i = 0; i < Hd; ++i) {
        h1v[i] = h1[off + i];
        float m0n = m0[off + i] + s0buf[off + i];
        m0v[i] = m0n;
        m1v[i] = m0n + s1buf[off + i];
        m0[off + i] = m0n;
        if (zeroPrev) s0buf[off + i] = 0.0f;
    }

    float a[15];
#pragma unroll
    for (int i = 0; i < Hd; ++i) { a[i] = h1v[i]; a[5 + i] = m0v[i]; a[10 + i] = m1v[i]; }

    float z[Hd], r[Hd];
#pragma unroll
    for (int i = 0; i < Hd; ++i) {
        float tz = gzb[i], tr = grb[i];
#pragma unroll
        for (int j = 0; j < 15; ++j) {
            tz = fmaf(a[j], gzW[j * Hd + i], tz);
            tr = fmaf(a[j], grW[j * Hd + i], tr);
        }
        z[i] = sigmoidf_(tz);
        r[i] = sigmoidf_(tr);
    }

    float joined[15];
#pragma unroll
    for (int i = 0; i < Hd; ++i) { joined[i] = r[i] * h1v[i]; joined[5 + i] = m0v[i]; joined[10 + i] = m1v[i]; }

#pragma unroll
    for (int i = 0; i < Hd; ++i) {
        float th = ghb[i];
#pragma unroll
        for (int j = 0; j < 15; ++j) th = fmaf(joined[j], ghW[j * Hd + i], th);
        float hh = tanhf(th);
        h1[off + i] = (1.0f - z[i]) * h1v[i] + z[i] * hh;
    }
}

// ---------------------------------------------------------------------------
// output MLP (unchanged, verified; runs once)
// ---------------------------------------------------------------------------
__global__ void __launch_bounds__(256, 1) out_kernel(
    const float* __restrict__ bnode, const float* __restrict__ h1,
    const float* __restrict__ oW1, const float* __restrict__ ob1,
    const float* __restrict__ oW2, const float* __restrict__ ob2,
    const float* __restrict__ oW3, const float* __restrict__ ob3,
    float* __restrict__ out)
{
    int t = blockIdx.x * 256 + threadIdx.x;
    if (t >= NBATCH * NN) return;

    float x[6];
#pragma unroll
    for (int i = 0; i < Hd; ++i) x[i] = h1[(size_t)t * Hd + i];
    x[5] = bnode[t];

    float acc[64];
#pragma unroll
    for (int q = 0; q < 64; ++q) acc[q] = ob2[q];

#pragma unroll 2
    for (int j = 0; j < 64; ++j) {
        float v = ob1[j];
#pragma unroll
        for (int f = 0; f < 6; ++f) v = fmaf(x[f], oW1[f * 64 + j], v);
        v = fmaxf(v, 0.0f);
        const float* __restrict__ w2r = oW2 + j * 64;
#pragma unroll
        for (int q = 0; q < 64; ++q) acc[q] = fmaf(v, w2r[q], acc[q]);
    }

    float o = ob3[0];
#pragma unroll
    for (int q = 0; q < 64; ++q) o = fmaf(fmaxf(acc[q], 0.0f), oW3[q], o);
    out[t] = sigmoidf_(o);
}

// ---------------------------------------------------------------------------
extern "C" void kernel_launch(void* const* d_in, const int* in_sizes, int n_in,
                              void* d_out, int out_size, void* d_ws, size_t ws_size,
                              hipStream_t stream) {
    const float* Jm    = (const float*)d_in[0];
    const float* bnode = (const float*)d_in[1];
    const int*   iin   = (const int*)d_in[2];
    const int*   iout  = (const int*)d_in[3];
    const float* mW1 = (const float*)d_in[4];
    const float* mb1 = (const float*)d_in[5];
    const float* mW2 = (const float*)d_in[6];
    const float* mb2 = (const float*)d_in[7];
    const float* mW3 = (const float*)d_in[8];
    const float* mb3 = (const float*)d_in[9];
    const float* gzW = (const float*)d_in[10];
    const float* gzb = (const float*)d_in[11];
    const float* grW = (const float*)d_in[12];
    const float* grb = (const float*)d_in[13];
    const float* ghW = (const float*)d_in[14];
    const float* ghb = (const float*)d_in[15];
    const float* oW1 = (const float*)d_in[16];
    const float* ob1 = (const float*)d_in[17];
    const float* oW2 = (const float*)d_in[18];
    const float* ob2 = (const float*)d_in[19];
    const float* oW3 = (const float*)d_in[20];
    const float* ob3 = (const float*)d_in[21];

    float* ws = (float*)d_ws;
    float* h1 = ws;
    float* m0 = ws + (size_t)BNH;
    float* sA = ws + (size_t)2 * BNH;
    float* sB = ws + (size_t)3 * BNH;
    unsigned* cnt  = (unsigned*)(ws + (size_t)4 * BNH);
    unsigned* cur  = cnt + NN;
    unsigned* row  = cur + NN;
    unsigned* perm = row + NN;
    int*      sout = (int*)(perm + EE);
    int*      sin  = sout + EE;
    float*    sJ   = (float*)(sin + EE);           // NBATCH*EE floats
    unsigned short* af1 = (unsigned short*)(sJ + (size_t)NBATCH * EE);  // 2048
    unsigned short* af2 = af1 + 2048;                                   // 4096
    unsigned short* af3 = af2 + 4096;                                   // 1024

    // zero h1, m0, sA, sB, cnt, cur (contiguous)
    hipMemsetAsync(d_ws, 0, ((size_t)4 * BNH + 2 * NN) * sizeof(float), stream);

    // one-time (per launch): sort edges by index_out + build weight frag images
    k_hist<<<EE / 256, 256, 0, stream>>>(iout, cnt);
    k_scan<<<1, 256, 0, stream>>>(cnt, row);
    k_scatter<<<EE / 256, 256, 0, stream>>>(iout, row, cur, perm);
    k_mat<<<EE / 256, 256, 0, stream>>>(perm, iout, iin, Jm, sout, sin, sJ);
    k_wfrag<<<20, 256, 0, stream>>>(mW1, mW2, mW3, af1, af2, af3);

    dim3 mgrid(EE / 256, NBATCH);
    int ngrid = (NBATCH * NN + 255) / 256;

    float* buf[2] = { sA, sB };
    for (int s = 0; s < 10; ++s) {
        float* sCur  = buf[s & 1];
        float* sPrev = (s == 0) ? sCur : buf[(s + 1) & 1];
        msg_kernel<<<mgrid, 256, 0, stream>>>(sJ, bnode, sin, sout,
                                              mb1, af1, af2, af3,
                                              mb2, mb3, h1, sCur);
        node_kernel<<<ngrid, 256, 0, stream>>>(gzW, gzb, grW, grb, ghW, ghb,
                                               h1, m0, sPrev, sCur,
                                               (s == 0) ? 0 : 1);
    }

    out_kernel<<<ngrid, 256, 0, stream>>>(bnode, h1,
                                          oW1, ob1, oW2, ob2, oW3, ob3,
                                          (float*)d_out);
}